// Round 9
// baseline (114.137 us; speedup 1.0000x reference)
//
#include <hip/hip_runtime.h>
#include <math.h>

// LowRankChristoffel: out = clip((((v@U)^2) @ W^T) * (1+sigmoid(x@Vw^T)), +-5)
// B=4, S=4096, D=2048, R=16, fp32. HBM floor ~50 us (with L3 help).
//
// R9: escape the two empirically-proven walls:
//  (a) 1024-thr WGs are hard-capped at 64 VGPR (R3/R4/R8) and never get a
//      2nd resident WG (R5) -> use 512-thr WGs (VGPR up to ~128, 2 WGs/CU
//      resident for any VGPR<=128).
//  (b) DS pipe ~36us/CU in R4 -> stage U^T as PACKED BF16 (64 KiB LDS,
//      ds_read_b64 instead of b128; fp32 accumulate; error ~1e-6 << 6.3e-6).
//  (c) depth-1 ping-pong register prefetch of v/x hides HBM latency
//      (affordable now: ~+32 VGPR at 512-thr).
// Phase 2 unchanged from R4/R6 (W fp32 in regs, 2 passes, nt f32x2 stores).

constexpr int D_DIM   = 2048;
constexpr int R_DIM   = 16;
constexpr int ROWS    = 16;      // rows per WG
constexpr int THREADS = 512;     // 8 waves
constexpr int RB      = 2;       // rows per wave

typedef float f32x2 __attribute__((ext_vector_type(2)));

// dynamic LDS: packed-bf16 U^T [16][1024] uints (64 KiB) + sq[16][16] + fac[16]
constexpr int U_U32 = R_DIM * (D_DIM / 2);
constexpr size_t SMEM_BYTES = (size_t)U_U32 * 4 + (size_t)ROWS * R_DIM * 4 + ROWS * 4;

__device__ __forceinline__ float clamp5(float v) {
    return fminf(fmaxf(v, -5.0f), 5.0f);
}
__device__ __forceinline__ float dot4(float4 a, float4 b) {
    return a.x * b.x + a.y * b.y + a.z * b.z + a.w * b.w;
}
// exact round-to-nearest-even fp32 -> bf16 bits (inputs are normal floats)
__device__ __forceinline__ unsigned int f2bf(float f) {
    unsigned int u = __float_as_uint(f);
    return (u + 0x7fffu + ((u >> 16) & 1u)) >> 16;
}

extern "C" __global__ void __launch_bounds__(THREADS)
lrc_kernel(const float* __restrict__ v, const float* __restrict__ x,
           const float* __restrict__ U, const float* __restrict__ W,
           const float* __restrict__ Vw, float* __restrict__ out, int nrows)
{
    extern __shared__ unsigned int smem_u[];
    unsigned int* u_lds = smem_u;                                  // [16][1024] packed pairs
    float* sq_lds  = reinterpret_cast<float*>(smem_u + U_U32);     // [ROWS][16]
    float* fac_lds = sq_lds + ROWS * R_DIM;                        // [ROWS]

    const int tid  = threadIdx.x;
    const int lane = tid & 63;
    const int wave = tid >> 6;          // 0..7
    const int row0 = blockIdx.x * ROWS;

    // ---- stage U^T as packed bf16: thread owns cols 4t..4t+3 (2 pairs) ----
    #pragma unroll
    for (int pr = 0; pr < 2; ++pr) {
        const int c = tid * 4 + pr * 2;
        float u0[R_DIM], u1[R_DIM];
        const float4* p0 = reinterpret_cast<const float4*>(U + (size_t)c * R_DIM);
        const float4* p1 = reinterpret_cast<const float4*>(U + (size_t)(c + 1) * R_DIM);
        #pragma unroll
        for (int q = 0; q < 4; ++q) {
            *reinterpret_cast<float4*>(&u0[q * 4]) = p0[q];
            *reinterpret_cast<float4*>(&u1[q * 4]) = p1[q];
        }
        #pragma unroll
        for (int r = 0; r < R_DIM; ++r)
            u_lds[r * (D_DIM / 2) + (c >> 1)] = f2bf(u0[r]) | (f2bf(u1[r]) << 16);
    }
    __syncthreads();

    // ---- phase 1: wave owns rows rl0, rl0+1; ping-pong prefetch of v/x ----
    {
        const int rl0 = wave * RB;
        const float* vb = v + (size_t)(row0 + rl0) * D_DIM;
        const float* xb = x + (size_t)(row0 + rl0) * D_DIM;
        const bool rows_ok = (row0 + rl0 + RB) <= nrows;

        float pp[RB][R_DIM];
        float xv[RB];
        #pragma unroll
        for (int k = 0; k < RB; ++k) {
            xv[k] = 0.0f;
            #pragma unroll
            for (int r = 0; r < R_DIM; ++r) pp[k][r] = 0.0f;
        }

        if (rows_ok) {
            float4 v4[2][RB], x4[2][RB];
            #pragma unroll
            for (int k = 0; k < RB; ++k) {   // preload iter 0
                v4[0][k] = *reinterpret_cast<const float4*>(vb + (size_t)k * D_DIM + lane * 4);
                x4[0][k] = *reinterpret_cast<const float4*>(xb + (size_t)k * D_DIM + lane * 4);
            }
            #pragma unroll
            for (int i = 0; i < D_DIM / 256; ++i) {      // 8 iters, statically unrolled
                const int cur = i & 1, nxt = cur ^ 1;
                const int d0 = i * 256 + lane * 4;
                if (i < D_DIM / 256 - 1) {               // issue next-iter loads early
                    const int dn = (i + 1) * 256 + lane * 4;
                    #pragma unroll
                    for (int k = 0; k < RB; ++k) {
                        v4[nxt][k] = *reinterpret_cast<const float4*>(vb + (size_t)k * D_DIM + dn);
                        x4[nxt][k] = *reinterpret_cast<const float4*>(xb + (size_t)k * D_DIM + dn);
                    }
                }
                const float4 vw4 = *reinterpret_cast<const float4*>(Vw + d0);  // L1-hot 8KB
                #pragma unroll
                for (int k = 0; k < RB; ++k) xv[k] += dot4(x4[cur][k], vw4);
                #pragma unroll
                for (int r = 0; r < R_DIM; ++r) {
                    const uint2 uu = *reinterpret_cast<const uint2*>(
                        u_lds + r * (D_DIM / 2) + (d0 >> 1));        // ds_read_b64
                    const float ua = __uint_as_float(uu.x << 16);
                    const float ub = __uint_as_float(uu.x & 0xffff0000u);
                    const float uc = __uint_as_float(uu.y << 16);
                    const float ud = __uint_as_float(uu.y & 0xffff0000u);
                    #pragma unroll
                    for (int k = 0; k < RB; ++k)
                        pp[k][r] += v4[cur][k].x * ua + v4[cur][k].y * ub
                                  + v4[cur][k].z * uc + v4[cur][k].w * ud;
                }
            }
        }

        // butterfly reduce across the 64-lane wave
        #pragma unroll
        for (int s = 32; s >= 1; s >>= 1) {
            #pragma unroll
            for (int k = 0; k < RB; ++k) {
                xv[k] += __shfl_xor(xv[k], s, 64);
                #pragma unroll
                for (int r = 0; r < R_DIM; ++r) pp[k][r] += __shfl_xor(pp[k][r], s, 64);
            }
        }
        if (lane == 0) {
            #pragma unroll
            for (int k = 0; k < RB; ++k) {
                const int rl = rl0 + k;
                #pragma unroll
                for (int r = 0; r < R_DIM; ++r)
                    sq_lds[rl * R_DIM + r] = pp[k][r] * pp[k][r];
                fac_lds[rl] = 1.0f + 1.0f / (1.0f + __expf(-xv[k]));
            }
        }
    }
    __syncthreads();

    // ---- phase 2: two d-passes; thread owns dd = p*1024 + 2*tid; W fp32 regs ----
    #pragma unroll
    for (int p = 0; p < 2; ++p) {
        const int dd = p * (2 * THREADS) + tid * 2;
        float w0[R_DIM], w1[R_DIM];
        const float4* p0 = reinterpret_cast<const float4*>(W + (size_t)dd * R_DIM);
        const float4* p1 = reinterpret_cast<const float4*>(W + (size_t)(dd + 1) * R_DIM);
        #pragma unroll
        for (int c = 0; c < 4; ++c) {
            *reinterpret_cast<float4*>(&w0[c * 4]) = p0[c];
            *reinterpret_cast<float4*>(&w1[c * 4]) = p1[c];
        }

        for (int rl = 0; rl < ROWS; ++rl) {
            if (row0 + rl >= nrows) break;
            float sqv[R_DIM];
            #pragma unroll
            for (int c = 0; c < 4; ++c)
                *reinterpret_cast<float4*>(&sqv[c * 4]) =
                    *reinterpret_cast<const float4*>(sq_lds + rl * R_DIM + c * 4);
            const float fac = fac_lds[rl];
            float o0 = 0.0f, o1 = 0.0f;
            #pragma unroll
            for (int r = 0; r < R_DIM; ++r) {
                o0 += sqv[r] * w0[r];
                o1 += sqv[r] * w1[r];
            }
            f32x2 o;
            o.x = clamp5(o0 * fac);
            o.y = clamp5(o1 * fac);
            __builtin_nontemporal_store(o,
                reinterpret_cast<f32x2*>(out + (size_t)(row0 + rl) * D_DIM + dd));
        }
    }
}

extern "C" void kernel_launch(void* const* d_in, const int* in_sizes, int n_in,
                              void* d_out, int out_size, void* d_ws, size_t ws_size,
                              hipStream_t stream) {
    const float* v  = (const float*)d_in[0];
    const float* x  = (const float*)d_in[1];
    const float* U  = (const float*)d_in[2];
    const float* W  = (const float*)d_in[3];
    const float* Vw = (const float*)d_in[4];
    float* out = (float*)d_out;

    const int nrows = in_sizes[0] / D_DIM;        // B*S = 16384
    const int grid  = (nrows + ROWS - 1) / ROWS;  // 1024 WGs -> 2 resident/CU

    (void)hipFuncSetAttribute((const void*)lrc_kernel,
                              hipFuncAttributeMaxDynamicSharedMemorySize,
                              (int)SMEM_BYTES);
    lrc_kernel<<<grid, THREADS, SMEM_BYTES, stream>>>(v, x, U, W, Vw, out, nrows);
}

// Round 10
// 105.435 us; speedup vs baseline: 1.0825x; 1.0825x over previous
//
#include <hip/hip_runtime.h>
#include <math.h>

// LowRankChristoffel via MFMA: proj = v@U as bf16 MFMA GEMM (v split hi+lo so
// only U's bf16 rounding remains ~1.9e-6, R9-measured), x@Vw in fp32 alongside,
// out = sq@W^T as K=16-padded 16x16x32 MFMA. No butterfly, no U-in-LDS, no
// DS streaming -- the structures that kept R1-R9 at >84 us.
//
// 1024 WGs x 256 thr (4 waves); wave w owns K-slice [w*512,+512) of the proj
// GEMM and d-slice [w*512,+512) of the output GEMM. LDS 5.4 KB -> 4 WG/CU.
//
// Fragment layouts (gfx950 v_mfma_f32_16x16x32_bf16):
//   A[m][k]: m = lane&15, k = (lane>>4)*8 + e   (e = vector elem 0..7)
//   B[k][n]: n = lane&15, k = (lane>>4)*8 + e
//   C/D:     n = lane&15, m = (lane>>4)*4 + i   (m89-verified)

typedef short bf16x8 __attribute__((ext_vector_type(8)));
typedef float f32x4  __attribute__((ext_vector_type(4)));

constexpr int D_DIM   = 2048;
constexpr int R_DIM   = 16;
constexpr int MROWS   = 16;    // rows per WG (one M-tile)
constexpr int THREADS = 256;   // 4 waves
constexpr int KSLICE  = 512;   // K per wave in phase A
constexpr int KSTEPS  = KSLICE / 32;

__device__ __forceinline__ unsigned f2bf(float f) {   // exact RTNE fp32->bf16
    unsigned u = __float_as_uint(f);
    return (u + 0x7fffu + ((u >> 16) & 1u)) >> 16;
}
__device__ __forceinline__ float bf2f(unsigned b) { return __uint_as_float(b << 16); }
__device__ __forceinline__ float clamp5(float v) { return fminf(fmaxf(v, -5.0f), 5.0f); }
__device__ __forceinline__ float dot4f(float4 a, float4 b) {
    return a.x * b.x + a.y * b.y + a.z * b.z + a.w * b.w;
}

extern "C" __global__ void __launch_bounds__(THREADS, 4)
lrc_mfma(const float* __restrict__ v, const float* __restrict__ x,
         const float* __restrict__ U, const float* __restrict__ W,
         const float* __restrict__ Vw, float* __restrict__ out, int nrows)
{
    __shared__ float proj_lds[4][MROWS][R_DIM];
    __shared__ float xv_lds[4][MROWS];
    __shared__ float sq_lds[MROWS][R_DIM];
    __shared__ float fac_lds[MROWS];

    const int tid  = threadIdx.x;
    const int lane = tid & 63;
    const int wave = tid >> 6;       // 0..3
    const int l16  = lane & 15;
    const int lk   = lane >> 4;      // 0..3
    const int row0 = blockIdx.x * MROWS;

    // ---- phase A: proj-tile MFMA over this wave's K-slice + fp32 x.Vw ----
    int grow = row0 + l16;           // A-row this lane loads
    if (grow >= nrows) grow = nrows - 1;
    const float* vp = v + (size_t)grow * D_DIM;
    const float* xp = x + (size_t)grow * D_DIM;

    f32x4 acc = {0.f, 0.f, 0.f, 0.f};
    float xv = 0.f;
    const int kbase = wave * KSLICE + lk * 8;

    #pragma unroll 4
    for (int s = 0; s < KSTEPS; ++s) {
        const int k = kbase + s * 32;
        const float4 va = *reinterpret_cast<const float4*>(vp + k);
        const float4 vb = *reinterpret_cast<const float4*>(vp + k + 4);
        const float4 xa = *reinterpret_cast<const float4*>(xp + k);
        const float4 xb = *reinterpret_cast<const float4*>(xp + k + 4);
        const float4 wa = *reinterpret_cast<const float4*>(Vw + k);
        const float4 wb = *reinterpret_cast<const float4*>(Vw + k + 4);

        // B-frag: U[k+e][l16], stride-16 scalar loads (L2-resident 128 KiB)
        const float* up = U + (size_t)k * R_DIM + l16;
        bf16x8 bu;
        #pragma unroll
        for (int e = 0; e < 8; ++e) bu[e] = (short)f2bf(up[e * R_DIM]);

        // A-frag hi/lo split of v (residual kills v-quantization error)
        const float vf[8] = {va.x, va.y, va.z, va.w, vb.x, vb.y, vb.z, vb.w};
        bf16x8 ah, al;
        #pragma unroll
        for (int e = 0; e < 8; ++e) {
            const unsigned h = f2bf(vf[e]);
            ah[e] = (short)h;
            al[e] = (short)f2bf(vf[e] - bf2f(h));
        }
        acc = __builtin_amdgcn_mfma_f32_16x16x32_bf16(ah, bu, acc, 0, 0, 0);
        acc = __builtin_amdgcn_mfma_f32_16x16x32_bf16(al, bu, acc, 0, 0, 0);

        xv += dot4f(xa, wa) + dot4f(xb, wb);
    }
    // x.Vw: sum the 4 lk-groups (rows stay lane-local)
    xv += __shfl_xor(xv, 16, 64);
    xv += __shfl_xor(xv, 32, 64);

    #pragma unroll
    for (int i = 0; i < 4; ++i) proj_lds[wave][lk * 4 + i][l16] = acc[i];
    if (lk == 0) xv_lds[wave][l16] = xv;
    __syncthreads();

    // ---- cross-wave reduce + square + sigmoid (256 threads = 16x16) ----
    {
        const int m = tid >> 4, r = tid & 15;
        const float p = proj_lds[0][m][r] + proj_lds[1][m][r]
                      + proj_lds[2][m][r] + proj_lds[3][m][r];
        sq_lds[m][r] = p * p;
        if (tid < MROWS) {
            const float s = xv_lds[0][tid] + xv_lds[1][tid]
                          + xv_lds[2][tid] + xv_lds[3][tid];
            fac_lds[tid] = 1.0f + 1.0f / (1.0f + __expf(-s));
        }
    }
    __syncthreads();

    // ---- phase C: out = sq @ W^T, one MFMA per 16-d chunk (K=16 padded) ----
    bf16x8 asq;
    #pragma unroll
    for (int e = 0; e < 8; ++e) {
        const int kk = lk * 8 + e;
        asq[e] = (kk < R_DIM) ? (short)f2bf(sq_lds[l16][kk]) : (short)0;
    }
    float fr[4];
    #pragma unroll
    for (int i = 0; i < 4; ++i) fr[i] = fac_lds[lk * 4 + i];

    #pragma unroll 4
    for (int c = 0; c < 32; ++c) {
        const int d0 = wave * 512 + c * 16;
        bf16x8 bw;
        if (lk < 2) {   // k = lk*8+e in 0..15 -> W[d0+l16][k]
            const float* wp = W + (size_t)(d0 + l16) * R_DIM + lk * 8;
            const float4 q0 = *reinterpret_cast<const float4*>(wp);
            const float4 q1 = *reinterpret_cast<const float4*>(wp + 4);
            bw[0] = (short)f2bf(q0.x); bw[1] = (short)f2bf(q0.y);
            bw[2] = (short)f2bf(q0.z); bw[3] = (short)f2bf(q0.w);
            bw[4] = (short)f2bf(q1.x); bw[5] = (short)f2bf(q1.y);
            bw[6] = (short)f2bf(q1.z); bw[7] = (short)f2bf(q1.w);
        } else {
            #pragma unroll
            for (int e = 0; e < 8; ++e) bw[e] = 0;
        }
        f32x4 o = {0.f, 0.f, 0.f, 0.f};
        o = __builtin_amdgcn_mfma_f32_16x16x32_bf16(asq, bw, o, 0, 0, 0);
        #pragma unroll
        for (int i = 0; i < 4; ++i) {
            const int rr = row0 + lk * 4 + i;
            if (rr < nrows)
                out[(size_t)rr * D_DIM + d0 + l16] = clamp5(o[i] * fr[i]);
        }
    }
}

extern "C" void kernel_launch(void* const* d_in, const int* in_sizes, int n_in,
                              void* d_out, int out_size, void* d_ws, size_t ws_size,
                              hipStream_t stream) {
    const float* v  = (const float*)d_in[0];
    const float* x  = (const float*)d_in[1];
    const float* U  = (const float*)d_in[2];
    const float* W  = (const float*)d_in[3];
    const float* Vw = (const float*)d_in[4];
    float* out = (float*)d_out;

    const int nrows = in_sizes[0] / D_DIM;          // B*S = 16384
    const int grid  = (nrows + MROWS - 1) / MROWS;  // 1024 WGs -> 4/CU

    lrc_mfma<<<grid, THREADS, 0, stream>>>(v, x, U, W, Vw, out, nrows);
}